// Round 4
// baseline (399.233 us; speedup 1.0000x reference)
//
#include <hip/hip_runtime.h>
#include <hip/hip_fp16.h>

#define OUT_UNITS 128
#define ROWS_PER_BLOCK 64     // one block per CU (grid = n_rows/64 = 256 = #CUs)
#define ROWS_PER_WAVE 8       // 8 waves x 8 rows
#define STAGE_ROWS 64         // w-rows per sweep stage
#define STAGE_BYTES (STAGE_ROWS * OUT_UNITS * 2)   // 16 KB fp16
#define CV_CAP 5120           // block nnz capacity (mean 3906, sigma 62 -> +19 sigma)

#define GLOBAL_AS __attribute__((address_space(1)))
#define LDS_AS    __attribute__((address_space(3)))

// ---------------- Kernel 0: fused prep (round-0 proven version) -------------
// job A (i < n4):  w fp32 -> fp16 into workspace (float4 -> 4 halves)
// job B (i < nnz): CSR row pointers from sorted COO rows
__global__ void prep(const float4* __restrict__ w4, uint2* __restrict__ wh, int n4,
                     const int* __restrict__ rows, int* __restrict__ row_start,
                     int nnz, int n_rows) {
    int i = blockIdx.x * blockDim.x + threadIdx.x;
    if (i < n4) {
        float4 f = w4[i];
        __half2 h01 = __floats2half2_rn(f.x, f.y);
        __half2 h23 = __floats2half2_rn(f.z, f.w);
        wh[i] = make_uint2(*(unsigned*)&h01, *(unsigned*)&h23);
    }
    if (i < nnz) {
        int cur = rows[i];
        if (i == 0) {
            for (int r = 0; r <= cur; ++r) row_start[r] = 0;
        } else {
            int prev = rows[i - 1];
            for (int r = prev + 1; r <= cur; ++r) row_start[r] = i;
        }
        if (i == nnz - 1) {
            for (int r = cur + 1; r <= n_rows; ++r) row_start[r] = nnz;
        }
    }
}

// ---------------- Kernel 1: table-sweep SpMM --------------------------------
// Round 17 redesign. Rounds 13/14/15 proved the random-gather path is walled
// at ~0.08 lines/cyc/CU (per-CU miss-slots x ~250cyc L2 latency) regardless
// of staging scheme (reg pipeline / LDS ring / nt policy: three-way tie at
// ~42 us). Fix: convert the RANDOM gather into a SEQUENTIAL stream. Each
// block (64 out-rows) stages its ~3900 nnz in LDS once, then sweeps the
// entire 2 MB wh table through a double-buffered 16 KB LDS stage via
// global_load_lds (counted vmcnt(2), never drained mid-loop). Per stage,
// each wave scans its 8 rows' nnz (1 ballot iter/row) and FMAs the ~0.5
// matching nnz/row/stage from LDS. Streaming runs at L2-stream rate
// (~56 B/cyc/CU vs gather's ~10): sweep = 2 MB/CU ~= 15.5 us floor; scan
// and FMA hide under it. Chip-wide 512 MB table re-read is served by the
// per-XCD L2 copy of the 2 MB table (32 TB/s < 34.5 TB/s L2 ceiling).
// Accumulation: lane owns cols {2*lane, 2*lane+1} of its wave's 8 rows ->
// acc statically indexed by the unrolled row loop (no scratch).
__global__ void spmm_sweep(const float* __restrict__ vals,
                           const __half* __restrict__ wh,
                           const int* __restrict__ cols,
                           const int* __restrict__ row_start,
                           float* __restrict__ out,
                           int n_rows, int nstages) {
    __shared__ unsigned short cv_c[CV_CAP];                   // 10 KB
    __shared__ float          cv_v[CV_CAP];                   // 20 KB
    __shared__ __align__(16) char wbuf[2][STAGE_BYTES];       // 32 KB  (total 62 KB)

    const int tid  = threadIdx.x;
    const int wave = tid >> 6;
    const int lane = tid & 63;
    const int b    = blockIdx.x;
    const int r0   = b * ROWS_PER_BLOCK;

    const int g0 = row_start[r0];
    const int g1 = row_start[r0 + ROWS_PER_BLOCK];

    // ---- phase 1: stage this block's (c, v) list into LDS ----
    for (int i = g0 + tid; i < g1; i += 512) {
        cv_c[i - g0] = (unsigned short)cols[i];
        cv_v[i - g0] = vals[i];
    }

    // per-wave row offsets (uniform scalar loads)
    const int wr0 = r0 + wave * ROWS_PER_WAVE;
    int off[ROWS_PER_WAVE + 1];
#pragma unroll
    for (int j = 0; j <= ROWS_PER_WAVE; ++j) off[j] = row_start[wr0 + j] - g0;

    const char* __restrict__ whb = (const char*)wh;

    // each wave stages 2 KB of each 16 KB stage: two 1 KB global_load_lds
#define ISSUE_STAGE(s)                                                          \
    do {                                                                        \
        const char* src_ = whb + (size_t)(s) * STAGE_BYTES + (wave << 11) + (lane << 4); \
        char* dst_ = &wbuf[(s) & 1][(wave << 11)];                              \
        __builtin_amdgcn_global_load_lds((const GLOBAL_AS void*)(src_),         \
                                         (LDS_AS void*)(dst_), 16, 0, 0);       \
        __builtin_amdgcn_global_load_lds((const GLOBAL_AS void*)(src_ + 1024),  \
                                         (LDS_AS void*)(dst_ + 1024), 16, 0, 0);\
    } while (0)

    float accx[ROWS_PER_WAVE], accy[ROWS_PER_WAVE];
#pragma unroll
    for (int j = 0; j < ROWS_PER_WAVE; ++j) { accx[j] = 0.f; accy[j] = 0.f; }

    // drain phase-1 traffic, publish cv to all waves
    asm volatile("s_waitcnt vmcnt(0) lgkmcnt(0)" ::: "memory");
    __syncthreads();

    ISSUE_STAGE(0);

    const __half2* wb0 = (const __half2*)&wbuf[0][0];
    const __half2* wb1 = (const __half2*)&wbuf[1][0];

    for (int s = 0; s < nstages; ++s) {
        if (s + 1 < nstages) {
            ISSUE_STAGE(s + 1);
            asm volatile("s_waitcnt vmcnt(2)" ::: "memory");  // stage s done; s+1 in flight
        } else {
            asm volatile("s_waitcnt vmcnt(0)" ::: "memory");
        }
        __syncthreads();   // all waves' stage-s chunks visible

        const __half2* wst = (s & 1) ? wb1 : wb0;   // + (c_local*64 + lane) half2
#pragma unroll
        for (int j = 0; j < ROWS_PER_WAVE; ++j) {
            for (int ii = off[j]; ii < off[j + 1]; ii += 64) {
                const int i = ii + lane;
                const bool valid = i < off[j + 1];
                const int c = valid ? (int)cv_c[i] : -1;
                const bool m = valid && ((c >> 6) == s);
                unsigned long long mask = __ballot(m);
                while (mask) {
                    const int bsrc = __ffsll((unsigned long long)mask) - 1;
                    mask &= mask - 1;
                    const int   cc = __shfl(c, bsrc);
                    const float vv = cv_v[ii + bsrc];              // broadcast read
                    const float2 f = __half22float2(wst[((cc & 63) << 6) + lane]);
                    accx[j] = fmaf(vv, f.x, accx[j]);
                    accy[j] = fmaf(vv, f.y, accy[j]);
                }
            }
        }
        __syncthreads();   // stage s fully consumed before buf[s&1] is re-issued
    }
#undef ISSUE_STAGE

    // ---- epilogue: lane owns cols {2*lane, 2*lane+1} of its wave's 8 rows ----
#pragma unroll
    for (int j = 0; j < ROWS_PER_WAVE; ++j) {
        float2* o = (float2*)(out + (size_t)(wr0 + j) * OUT_UNITS + (lane << 1));
        *o = make_float2(accx[j], accy[j]);
    }
}

extern "C" void kernel_launch(void* const* d_in, const int* in_sizes, int n_in,
                              void* d_out, int out_size, void* d_ws, size_t ws_size,
                              hipStream_t stream) {
    const float* vals = (const float*)d_in[0];
    const float* w    = (const float*)d_in[1];
    const int*   rows = (const int*)d_in[2];
    const int*   cols = (const int*)d_in[3];
    float* out = (float*)d_out;

    const int nnz      = in_sizes[0];
    const int n_rows   = out_size / OUT_UNITS;        // 16384
    const int w_n      = in_sizes[1];                 // 8192*128
    const int n4       = w_n / 4;
    const int inp      = w_n / OUT_UNITS;             // 8192
    const int nstages  = inp / STAGE_ROWS;            // 128

    // ws layout: [0, 64KB+4) row_start ; [128KB, 128KB+2MB) w fp16
    int*    row_start = (int*)d_ws;
    __half* wh        = (__half*)((char*)d_ws + (128 << 10));

    const int prep_threads = (nnz > n4) ? nnz : n4;
    prep<<<(prep_threads + 255) / 256, 256, 0, stream>>>(
        (const float4*)w, (uint2*)wh, n4, rows, row_start, nnz, n_rows);
    spmm_sweep<<<n_rows / ROWS_PER_BLOCK, 512, 0, stream>>>(
        vals, wh, cols, row_start, out, n_rows, nstages);
}

// Round 5
// 132.911 us; speedup vs baseline: 3.0038x; 3.0038x over previous
//
#include <hip/hip_runtime.h>
#include <hip/hip_fp16.h>

#define OUT_UNITS 128
#define RPB 64                 // rows per block (grid 256 = 1 block/CU)
#define NTHREADS 1024          // 16 waves
#define NW 16
#define SROWS 128              // w-rows per sweep stage
#define SBYTES (SROWS * OUT_UNITS * 2)   // 32 KB fp16
#define NSTAGES 64             // 8192 / 128
#define NKEY (NSTAGES * RPB)   // 4096 (stage, rowInBlock)
#define CV_CAP 4864            // block nnz: mean 4096, sigma ~64 -> +12 sigma

#define GLOBAL_AS __attribute__((address_space(1)))
#define LDS_AS    __attribute__((address_space(3)))

// ---------------- Kernel 0: fused prep (round-0 proven) ---------------------
__global__ void prep(const float4* __restrict__ w4, uint2* __restrict__ wh, int n4,
                     const int* __restrict__ rows, int* __restrict__ row_start,
                     int nnz, int n_rows) {
    int i = blockIdx.x * blockDim.x + threadIdx.x;
    if (i < n4) {
        float4 f = w4[i];
        __half2 h01 = __floats2half2_rn(f.x, f.y);
        __half2 h23 = __floats2half2_rn(f.z, f.w);
        wh[i] = make_uint2(*(unsigned*)&h01, *(unsigned*)&h23);
    }
    if (i < nnz) {
        int cur = rows[i];
        if (i == 0) {
            for (int r = 0; r <= cur; ++r) row_start[r] = 0;
        } else {
            int prev = rows[i - 1];
            for (int r = prev + 1; r <= cur; ++r) row_start[r] = i;
        }
        if (i == nnz - 1) {
            for (int r = cur + 1; r <= n_rows; ++r) row_start[r] = nnz;
        }
    }
}

// ---------------- Kernel 1: bucketed table-sweep SpMM -----------------------
// Round-4 lesson: the sweep's STREAM works (FETCH 12.4 MB, table L2-fed);
// the per-stage SCAN died (O(nnz*nstages) + serial shfl/LDS chains ->
// 6300 cyc/stage). Round 5: counting-sort the block's nnz by
// key=(stage, rowInBlock) once (O(nnz)), then each stage each quarter-wave
// walks only its own pre-bucketed segment (avg 1 entry): no ballot, no
// shfl, static accumulator (quarter owns its row), one contiguous
// ds_read_b128 per entry (256B slice covers all banks, conflict-free).
// Stages are 32 KB / 128 w-rows (64 stages), ring-3 LDS buffering via
// global_load_lds with counted vmcnt(2) (never drained mid-loop),
// 1 barrier/stage. 16 waves for latency hiding; 1 block/CU by LDS.
__global__ __launch_bounds__(NTHREADS, 4)
void spmm_sweep2(const float* __restrict__ vals,
                 const __half* __restrict__ wh,
                 const int* __restrict__ cols,
                 const int* __restrict__ row_start,
                 float* __restrict__ out) {
    __shared__ __align__(16) char wbuf[3][SBYTES];   // 96 KB ring
    __shared__ unsigned char cv_c[CV_CAP];           // c & 127 (within stage)
    __shared__ float         cv_v[CV_CAP];
    __shared__ unsigned lptr[NKEY + 1];              // bucket starts (excl prefix)
    __shared__ unsigned lcur[NKEY];                  // scatter cursors
    __shared__ unsigned wtot[NW], woff[NW];

    const int tid     = threadIdx.x;
    const int wave    = __builtin_amdgcn_readfirstlane(tid >> 6);
    const int lane    = tid & 63;
    const int quarter = lane >> 4;     // row within wave's 4
    const int sub     = lane & 15;     // 16 lanes x 8 halves = 128 cols
    const int r0      = blockIdx.x * RPB;

    // ---- zero histogram ----
    for (int k = tid; k < NKEY; k += NTHREADS) lptr[k] = 0;
    __syncthreads();

    // wave's 4 row extents
    int rs[5];
#pragma unroll
    for (int j = 0; j <= 4; ++j) rs[j] = row_start[r0 + wave * 4 + j];
    const int g0 = row_start[r0];

    // ---- pass 1: histogram over (stage, rowInBlock) ----
#pragma unroll
    for (int j = 0; j < 4; ++j) {
        for (int i = rs[j] + lane; i < rs[j + 1]; i += 64) {
            int c = cols[i];
            atomicAdd(&lptr[(c >> 7) * 64 + wave * 4 + j], 1u);
        }
    }
    __syncthreads();

    // ---- exclusive prefix sum over 4096 keys (in place), copy to lcur ----
    unsigned h[4], lsum = 0;
    const int kb = wave * 256 + lane * 4;
#pragma unroll
    for (int t = 0; t < 4; ++t) { h[t] = lptr[kb + t]; lsum += h[t]; }
    unsigned sc = lsum;
#pragma unroll
    for (int d = 1; d < 64; d <<= 1) {
        unsigned u = __shfl_up(sc, d);
        if (lane >= d) sc += u;
    }
    if (lane == 63) wtot[wave] = sc;
    const unsigned lex = sc - lsum;          // exclusive within wave
    __syncthreads();
    if (wave == 0 && lane < NW) {
        unsigned t = wtot[lane];
        unsigned s2 = t;
#pragma unroll
        for (int d = 1; d < NW; d <<= 1) {
            unsigned u = __shfl_up(s2, d);
            if (lane >= d) s2 += u;
        }
        woff[lane] = s2 - t;                 // exclusive across waves
    }
    __syncthreads();
    unsigned base = woff[wave] + lex;
#pragma unroll
    for (int t = 0; t < 4; ++t) {
        lptr[kb + t] = base;
        lcur[kb + t] = base;
        base += h[t];
    }
    if (tid == 0) lptr[NKEY] = (unsigned)(row_start[r0 + RPB] - g0);
    __syncthreads();

    // ---- pass 2: scatter (c_local, v) into bucketed order ----
#pragma unroll
    for (int j = 0; j < 4; ++j) {
        for (int i = rs[j] + lane; i < rs[j + 1]; i += 64) {
            int c = cols[i];
            float v = vals[i];
            unsigned pos = atomicAdd(&lcur[(c >> 7) * 64 + wave * 4 + j], 1u);
            cv_c[pos] = (unsigned char)(c & 127);
            cv_v[pos] = v;
        }
    }
    __syncthreads();

    const char* __restrict__ whb = (const char*)wh;

    // each wave stages 2 KB of each 32 KB stage: two 1 KB global_load_lds
#define ISSUE(s)                                                               \
    do {                                                                       \
        const char* src_ = whb + (size_t)(s) * SBYTES + (wave << 11) + (lane << 4); \
        char* dst_ = &wbuf[(s) % 3][wave << 11];                               \
        __builtin_amdgcn_global_load_lds((const GLOBAL_AS void*)src_,          \
                                         (LDS_AS void*)dst_, 16, 0, 0);        \
        __builtin_amdgcn_global_load_lds((const GLOBAL_AS void*)(src_ + 1024), \
                                         (LDS_AS void*)(dst_ + 1024), 16, 0, 0);\
    } while (0)

    float4 accA = make_float4(0.f, 0.f, 0.f, 0.f);  // cols sub*8 + 0..3
    float4 accB = make_float4(0.f, 0.f, 0.f, 0.f);  // cols sub*8 + 4..7

    ISSUE(0); ISSUE(1);

    const int kq0 = wave * 4 + quarter;
    for (int s = 0; s < NSTAGES; ++s) {
        // own stage-s loads done; stage-(s+1) loads stay in flight
        if (s < NSTAGES - 1) asm volatile("s_waitcnt vmcnt(2)" ::: "memory");
        else                 asm volatile("s_waitcnt vmcnt(0)" ::: "memory");
        __syncthreads();     // all waves' chunks of stage s visible
        // refill slot of stage s-1 (consumed by all before this barrier)
        if (s + 2 < NSTAGES) ISSUE(s + 2);

        const char* wst = &wbuf[s % 3][0];
        int p  = (int)lptr[s * 64 + kq0];
        int pe = (int)lptr[s * 64 + kq0 + 1];
        for (; p < pe; ++p) {
            float v  = cv_v[p];
            int   cl = cv_c[p];
            uint4 q4 = *(const uint4*)(wst + (cl << 8) + (sub << 4));
            const __half2* hh = (const __half2*)&q4;
            float2 f0 = __half22float2(hh[0]);
            float2 f1 = __half22float2(hh[1]);
            float2 f2 = __half22float2(hh[2]);
            float2 f3 = __half22float2(hh[3]);
            accA.x = fmaf(v, f0.x, accA.x); accA.y = fmaf(v, f0.y, accA.y);
            accA.z = fmaf(v, f1.x, accA.z); accA.w = fmaf(v, f1.y, accA.w);
            accB.x = fmaf(v, f2.x, accB.x); accB.y = fmaf(v, f2.y, accB.y);
            accB.z = fmaf(v, f3.x, accB.z); accB.w = fmaf(v, f3.y, accB.w);
        }
    }
#undef ISSUE

    // ---- epilogue: quarter q owns row r0 + wave*4 + q; lane covers 8 cols ----
    float* orow = out + (size_t)(r0 + wave * 4 + quarter) * OUT_UNITS + (sub << 3);
    *(float4*)orow = accA;
    *((float4*)(orow + 4)) = accB;
}

extern "C" void kernel_launch(void* const* d_in, const int* in_sizes, int n_in,
                              void* d_out, int out_size, void* d_ws, size_t ws_size,
                              hipStream_t stream) {
    const float* vals = (const float*)d_in[0];
    const float* w    = (const float*)d_in[1];
    const int*   rows = (const int*)d_in[2];
    const int*   cols = (const int*)d_in[3];
    float* out = (float*)d_out;

    const int nnz    = in_sizes[0];
    const int n_rows = out_size / OUT_UNITS;  // 16384
    const int w_n    = in_sizes[1];           // 8192*128
    const int n4     = w_n / 4;

    // ws layout: [0, 64KB+4) row_start ; [128KB, 128KB+2MB) w fp16
    int*    row_start = (int*)d_ws;
    __half* wh        = (__half*)((char*)d_ws + (128 << 10));

    const int prep_threads = (nnz > n4) ? nnz : n4;
    prep<<<(prep_threads + 255) / 256, 256, 0, stream>>>(
        (const float4*)w, (uint2*)wh, n4, rows, row_start, nnz, n_rows);
    spmm_sweep2<<<n_rows / RPB, NTHREADS, 0, stream>>>(
        vals, wh, cols, row_start, out);
}